// Round 13
// baseline (41.005 us; speedup 1.0000x reference)
//
#include <hip/hip_runtime.h>
#include <hip/hip_fp16.h>
#include <math.h>

#define E_NUMC 100000
#define DIMC 32
#define NEIGHC 16
#define RULESC 8

struct __align__(16) h2x4 { __half2 x, y, z, w; };
struct __align__(8)  h2x2 { __half2 x, y; };

typedef _Float16 half8 __attribute__((ext_vector_type(8)));
typedef float    floatx4 __attribute__((ext_vector_type(4)));
typedef float    fx2 __attribute__((ext_vector_type(2)));

// ---------------------------------------------------------------------------
// Pre-pass: fp8 e4m3 renormed embedding table (32 B/row, 3.2 MB ->
// per-XCD-L2-resident) + W converted to fp16 global (4 KB, L1-hot later).
// hop1/user/item rows are read from the ORIGINAL fp32 table in kernel 1.
// ---------------------------------------------------------------------------
__global__ __launch_bounds__(256) void renorm_kernel(
    const float* __restrict__ emb, short* __restrict__ o8,
    const float* __restrict__ W, _Float16* __restrict__ Whg)
{
    if (blockIdx.x == 0) {
        const float4* W4 = (const float4*)W;
        const int o = threadIdx.x >> 3, oct = threadIdx.x & 7;
        const float4 wa = W4[o * 16 + 2 * oct];
        const float4 wb = W4[o * 16 + 2 * oct + 1];
        half8 hw;
        hw[0] = (_Float16)wa.x; hw[1] = (_Float16)wa.y;
        hw[2] = (_Float16)wa.z; hw[3] = (_Float16)wa.w;
        hw[4] = (_Float16)wb.x; hw[5] = (_Float16)wb.y;
        hw[6] = (_Float16)wb.z; hw[7] = (_Float16)wb.w;
        *(half8*)&Whg[o * 64 + 8 * oct] = hw;
    }
    const int row = blockIdx.x * 16 + (threadIdx.x >> 4);
    const int j = threadIdx.x & 15;
    const float2 f = ((const float2*)(emb + (long)row * DIMC))[j];
    float sq = f.x * f.x + f.y * f.y;
    sq += __shfl_xor(sq, 1, 64);
    sq += __shfl_xor(sq, 2, 64);
    sq += __shfl_xor(sq, 4, 64);
    sq += __shfl_xor(sq, 8, 64);
    const float s = fminf(1.0f, 1.0f / fmaxf(sqrtf(sq), 1e-7f));
    const int pk = __builtin_amdgcn_cvt_pk_fp8_f32(f.x * s, f.y * s, 0, false);
    o8[(long)row * (DIMC / 2) + j] = (short)(pk & 0xffff);
}

// ---------------------------------------------------------------------------
// Kernel 1: ONE WAVE = ONE (batch, rule) tree. 4 independent waves per
// 256-thread block (rule = blockIdx.y*4 + wave), ZERO __syncthreads.
// Lane owns (node m = lane>>2, dim-chunk q = lane&3):
//   - e2 ids: one coalesced int4 per lane (children 4q..4q+3 of node m)
//   - phase B: 16 fp8 uint2 gathers (2 batches of 8), fp32 accumulate ->
//     lane owns the full mean2 chunk, no shuffles needed
//   - phase C: 17 fp32 rows renormed by 8-lane groups; mean1 via register
//     partials + 3 shfl
//   - MFMA (4x 16x16x32_f16, B-frags direct from global Whg), v0, E in-wave
// One scalar out per tree (item-dot folded in; linearity).
// __launch_bounds__(256,8): target <=64 VGPR -> 32 waves/CU = 32 trees/CU.
// ---------------------------------------------------------------------------
__global__ __launch_bounds__(256, 8) void rgrec_tree1w_kernel(
    const int* __restrict__ users, const int* __restrict__ items,
    const int* __restrict__ rules, const int* __restrict__ adj,
    const float* __restrict__ emb, const uint2* __restrict__ emb8,
    const _Float16* __restrict__ Whg, const float* __restrict__ bvec,
    float* __restrict__ resS)
{
    const int b = blockIdx.x;
    const int t = threadIdx.x;
    const int wave = t >> 6;
    const int lane = t & 63;
    const int r = blockIdx.y * 4 + wave;

    __shared__ _Float16 Xh[4][17][72];   // per wave: rows 0..15 = [h1|mean2], 16 = [u|mean1]
    __shared__ float    xe[4][68];       // per wave: [v0 | meanv1]

    const int user = users[b];
    const int rid0 = rules[r * 2 + 0];
    const int rid1 = rules[r * 2 + 1];

    // ---- hop1 ids (lanes 0..15), then e2 ids: one int4 per lane ----
    int h1v = 0;
    if (lane < 16) h1v = adj[(rid0 * E_NUMC + user) * NEIGHC + lane];

    const int m = lane >> 2, q = lane & 3;
    const int e1m = __shfl(h1v, m, 64);
    const int4 e2q = ((const int4*)(adj + ((long)rid1 * E_NUMC + e1m) * NEIGHC))[q];

    // ---- item value (o = lane&31), renormed, kept in register ----
    float itv;
    {
        const int it = items[b];
        itv = emb[(long)it * DIMC + (lane & 31)];
        float sq = itv * itv;
        sq += __shfl_xor(sq, 1, 64);
        sq += __shfl_xor(sq, 2, 64);
        sq += __shfl_xor(sq, 4, 64);
        sq += __shfl_xor(sq, 8, 64);
        sq += __shfl_xor(sq, 16, 64);
        itv *= fminf(1.0f, 1.0f / fmaxf(sqrtf(sq), 1e-7f));
    }

    // ---- phase B: 16 children x uint2 (dims 8q..8q+7), 2 batches of 8 ----
    const float sc = 1.0f / 16.0f;
    {
        float acc[8];
#pragma unroll
        for (int d = 0; d < 8; ++d) acc[d] = 0.0f;
#pragma unroll
        for (int half = 0; half < 2; ++half) {
            uint2 vb[8];
#pragma unroll
            for (int s = 0; s < 8; ++s) {
                const int c = half * 8 + s;
                const int comp = c & 3;
                const int src = (m << 2) + (c >> 2);
                const int ec = __shfl(comp == 0 ? e2q.x : comp == 1 ? e2q.y :
                                      comp == 2 ? e2q.z : e2q.w, src, 64);
                vb[s] = emb8[(long)ec * 4 + q];
            }
#pragma unroll
            for (int s = 0; s < 8; ++s) {
                const fx2 p0 = __builtin_amdgcn_cvt_pk_f32_fp8(vb[s].x, false);
                const fx2 p1 = __builtin_amdgcn_cvt_pk_f32_fp8(vb[s].x, true);
                const fx2 p2 = __builtin_amdgcn_cvt_pk_f32_fp8(vb[s].y, false);
                const fx2 p3 = __builtin_amdgcn_cvt_pk_f32_fp8(vb[s].y, true);
                acc[0] += p0[0]; acc[1] += p0[1];
                acc[2] += p1[0]; acc[3] += p1[1];
                acc[4] += p2[0]; acc[5] += p2[1];
                acc[6] += p3[0]; acc[7] += p3[1];
            }
        }
        h2x4 st;
        st.x = __floats2half2_rn(acc[0] * sc, acc[1] * sc);
        st.y = __floats2half2_rn(acc[2] * sc, acc[3] * sc);
        st.z = __floats2half2_rn(acc[4] * sc, acc[5] * sc);
        st.w = __floats2half2_rn(acc[6] * sc, acc[7] * sc);
        *(h2x4*)&Xh[wave][m][32 + 8 * q] = st;
    }

    // ---- phase C: 17 rows (16 h1 + user), 8 lanes/row; mean1 partials ----
    {
        const int k8 = lane & 7;
        float ps0 = 0.f, ps1 = 0.f, ps2 = 0.f, ps3 = 0.f;
#pragma unroll
        for (int it3 = 0; it3 < 3; ++it3) {
            const int g2 = it3 * 8 + (lane >> 3);
            const int eh = __shfl(h1v, g2 & 15, 64);
            if (g2 <= 16) {
                const int e = (g2 < 16) ? eh : user;
                const float4 f = ((const float4*)(emb + (long)e * DIMC))[k8];
                float sq = f.x * f.x + f.y * f.y + f.z * f.z + f.w * f.w;
                sq += __shfl_xor(sq, 1, 64);
                sq += __shfl_xor(sq, 2, 64);
                sq += __shfl_xor(sq, 4, 64);
                const float s = fminf(1.0f, 1.0f / fmaxf(sqrtf(sq), 1e-7f));
                const float c0 = f.x * s, c1 = f.y * s;
                const float c2 = f.z * s, c3 = f.w * s;
                *(__half2*)&Xh[wave][g2][4 * k8]     = __floats2half2_rn(c0, c1);
                *(__half2*)&Xh[wave][g2][4 * k8 + 2] = __floats2half2_rn(c2, c3);
                if (g2 < 16) { ps0 += c0; ps1 += c1; ps2 += c2; ps3 += c3; }
            }
        }
        // mean1: sum across lanes with equal k8 (rows j and 8+j per lane)
        ps0 += __shfl_xor(ps0, 8, 64);  ps1 += __shfl_xor(ps1, 8, 64);
        ps2 += __shfl_xor(ps2, 8, 64);  ps3 += __shfl_xor(ps3, 8, 64);
        ps0 += __shfl_xor(ps0, 16, 64); ps1 += __shfl_xor(ps1, 16, 64);
        ps2 += __shfl_xor(ps2, 16, 64); ps3 += __shfl_xor(ps3, 16, 64);
        ps0 += __shfl_xor(ps0, 32, 64); ps1 += __shfl_xor(ps1, 32, 64);
        ps2 += __shfl_xor(ps2, 32, 64); ps3 += __shfl_xor(ps3, 32, 64);
        if (lane < 8) {
            *(__half2*)&Xh[wave][16][32 + 4 * k8] =
                __floats2half2_rn(ps0 * sc, ps1 * sc);
            *(__half2*)&Xh[wave][16][32 + 4 * k8 + 2] =
                __floats2half2_rn(ps2 * sc, ps3 * sc);
        }
    }

    // ---- phase D: 4 MFMA in-wave; meanv1 from C-fragments ----
    const int cn = lane & 15, kg = lane >> 4;
    {
        const half8 a0 = *(const half8*)&Xh[wave][cn][8 * kg];
        const half8 a1 = *(const half8*)&Xh[wave][cn][32 + 8 * kg];
#pragma unroll
        for (int nh = 0; nh < 2; ++nh) {
            const half8 b0 = *(const half8*)&Whg[(cn + 16 * nh) * 64 + 8 * kg];
            const half8 b1 = *(const half8*)&Whg[(cn + 16 * nh) * 64 + 32 + 8 * kg];
            floatx4 acc4 = {0.0f, 0.0f, 0.0f, 0.0f};
            acc4 = __builtin_amdgcn_mfma_f32_16x16x32_f16(a0, b0, acc4, 0, 0, 0);
            acc4 = __builtin_amdgcn_mfma_f32_16x16x32_f16(a1, b1, acc4, 0, 0, 0);
            const float bb = bvec[cn + 16 * nh];
            float cs = 0.0f;
#pragma unroll
            for (int e = 0; e < 4; ++e) cs += fmaxf(acc4[e] + bb, 0.0f);
            cs += __shfl_xor(cs, 16, 64);
            cs += __shfl_xor(cs, 32, 64);
            if (lane < 16) xe[wave][32 + cn + 16 * nh] = cs * sc;
        }
    }

    // ---- v0 = relu(W [u | mean1] + b): o = lane&31, halves over d ----
    const int o = lane & 31, hh = lane >> 5;
    {
        float a = 0.0f;
#pragma unroll
        for (int oct = 4 * hh; oct < 4 * hh + 4; ++oct) {
            const half8 u = *(const half8*)&Xh[wave][16][8 * oct];
            const half8 w = *(const half8*)&Whg[o * 64 + 8 * oct];
#pragma unroll
            for (int e = 0; e < 8; ++e) a += (float)u[e] * (float)w[e];
        }
        a += __shfl_xor(a, 32, 64);
        if (hh == 0) xe[wave][o] = fmaxf(a + bvec[o], 0.0f);
    }

    // ---- phase E + item dot: one scalar out ----
    {
        float a = 0.0f;
#pragma unroll
        for (int oct = 4 * hh; oct < 4 * hh + 4; ++oct) {
            const half8 w = *(const half8*)&Whg[o * 64 + 8 * oct];
            const float4 xa = *(const float4*)&xe[wave][8 * oct];
            const float4 xb = *(const float4*)&xe[wave][8 * oct + 4];
            a += (float)w[0] * xa.x + (float)w[1] * xa.y
               + (float)w[2] * xa.z + (float)w[3] * xa.w
               + (float)w[4] * xb.x + (float)w[5] * xb.y
               + (float)w[6] * xb.z + (float)w[7] * xb.w;
        }
        a += __shfl_xor(a, 32, 64);
        float p = (hh == 0) ? tanhf(a + bvec[o]) * itv : 0.0f;
        p += __shfl_xor(p, 1, 64);
        p += __shfl_xor(p, 2, 64);
        p += __shfl_xor(p, 4, 64);
        p += __shfl_xor(p, 8, 64);
        p += __shfl_xor(p, 16, 64);
        if (lane == 0) resS[b * RULESC + r] = p;
    }
}

// ---------------------------------------------------------------------------
// Kernel 2 (tiny): out[b] = sigmoid( rws * sum_r rule_w[r] * resS[b][r] )
// ---------------------------------------------------------------------------
__global__ __launch_bounds__(256) void rgrec_sig_kernel(
    const float* __restrict__ rule_w, const float* __restrict__ resS,
    float* __restrict__ out, int B)
{
    const int b = blockIdx.x * 256 + threadIdx.x;
    if (b >= B) return;

    float ss = 0.0f;
    float rw[RULESC];
#pragma unroll
    for (int i = 0; i < RULESC; ++i) { rw[i] = rule_w[i]; ss += rw[i] * rw[i]; }
    const float rws = fminf(1.0f, 1.0f / fmaxf(sqrtf(ss), 1e-7f));

    const float4 r0 = ((const float4*)(resS + b * RULESC))[0];
    const float4 r1 = ((const float4*)(resS + b * RULESC))[1];
    const float acc = rw[0] * r0.x + rw[1] * r0.y + rw[2] * r0.z + rw[3] * r0.w
                    + rw[4] * r1.x + rw[5] * r1.y + rw[6] * r1.z + rw[7] * r1.w;
    out[b] = 1.0f / (1.0f + expf(-acc * rws));
}

// ---------------------------------------------------------------------------
// Fallback fused fp32 kernel (known-good) if d_ws is too small.
// ---------------------------------------------------------------------------
__global__ __launch_bounds__(256) void rgrec_fused_kernel(
    const int* __restrict__ users, const int* __restrict__ items,
    const int* __restrict__ rules, const int* __restrict__ adj,
    const float* __restrict__ emb, const float* __restrict__ rule_w,
    const float* __restrict__ W, const float* __restrict__ bvec,
    float* __restrict__ out)
{
    const int b = blockIdx.x;
    const int t = threadIdx.x;

    __shared__ float Wt[64][33];
    __shared__ float bs[32];
    __shared__ float h1s[16][33];
    __shared__ float mean2[16][33];
    __shared__ float v1[16][33];
    __shared__ float u_vec[32];
    __shared__ float mean1[32];
    __shared__ float v0[32];
    __shared__ float meanv1[32];
    __shared__ float useru[32];
    __shared__ int   h1id[16];

    for (int i = t; i < 64 * 32; i += 256) {
        const int o = i >> 6, d = i & 63;
        Wt[d][o] = W[i];
    }
    if (t < 32) { bs[t] = bvec[t]; useru[t] = 0.0f; }

    float ss = 0.0f;
#pragma unroll
    for (int i = 0; i < RULESC; ++i) { const float w = rule_w[i]; ss += w * w; }
    const float rws = fminf(1.0f, 1.0f / fmaxf(sqrtf(ss), 1e-7f));

    const int user = users[b];

    for (int r = 0; r < RULESC; ++r) {
        const int rid0 = rules[r * 2 + 0];
        const int rid1 = rules[r * 2 + 1];
        if (t < 16) h1id[t] = adj[(rid0 * E_NUMC + user) * NEIGHC + t];
        __syncthreads();
        {
            const int m = t >> 4, j = t & 15;
            const int e1 = h1id[m];
            const int e2 = adj[(rid1 * E_NUMC + e1) * NEIGHC + j];
            float v[32];
            const float4* p = (const float4*)(emb + (long)e2 * DIMC);
            float sq = 0.0f;
#pragma unroll
            for (int q = 0; q < 8; ++q) {
                const float4 f = p[q];
                v[q * 4 + 0] = f.x; v[q * 4 + 1] = f.y;
                v[q * 4 + 2] = f.z; v[q * 4 + 3] = f.w;
                sq += f.x * f.x + f.y * f.y + f.z * f.z + f.w * f.w;
            }
            const float s =
                fminf(1.0f, 1.0f / fmaxf(sqrtf(sq), 1e-7f)) * (1.0f / 16.0f);
#pragma unroll
            for (int d = 0; d < 32; ++d) v[d] *= s;
#pragma unroll
            for (int st = 1; st < 16; st <<= 1) {
#pragma unroll
                for (int d = 0; d < 32; ++d) v[d] += __shfl_xor(v[d], st, 64);
            }
            mean2[m][j]      = v[j];
            mean2[m][j + 16] = v[j + 16];
        }
        if (t < 136) {
            const int g = t >> 3, k = t & 7;
            const int e = (g < 16) ? h1id[g] : user;
            const float4 f = ((const float4*)(emb + (long)e * DIMC))[k];
            float sq = f.x * f.x + f.y * f.y + f.z * f.z + f.w * f.w;
            sq += __shfl_xor(sq, 1, 64);
            sq += __shfl_xor(sq, 2, 64);
            sq += __shfl_xor(sq, 4, 64);
            const float s = fminf(1.0f, 1.0f / fmaxf(sqrtf(sq), 1e-7f));
            if (g < 16) {
                h1s[g][k * 4 + 0] = f.x * s; h1s[g][k * 4 + 1] = f.y * s;
                h1s[g][k * 4 + 2] = f.z * s; h1s[g][k * 4 + 3] = f.w * s;
            } else {
                u_vec[k * 4 + 0] = f.x * s; u_vec[k * 4 + 1] = f.y * s;
                u_vec[k * 4 + 2] = f.z * s; u_vec[k * 4 + 3] = f.w * s;
            }
        }
        __syncthreads();
        {
            const int m = t >> 4, o = t & 15;
            float a0 = bs[o], a1 = bs[o + 16];
#pragma unroll
            for (int d = 0; d < 32; ++d) {
                const float h = h1s[m][d];
                a0 += Wt[d][o] * h;
                a1 += Wt[d][o + 16] * h;
            }
#pragma unroll
            for (int d = 0; d < 32; ++d) {
                const float h = mean2[m][d];
                a0 += Wt[32 + d][o] * h;
                a1 += Wt[32 + d][o + 16] * h;
            }
            v1[m][o]      = fmaxf(a0, 0.0f);
            v1[m][o + 16] = fmaxf(a1, 0.0f);
        }
        if (t < 32) {
            float mn = 0.0f;
#pragma unroll
            for (int m2 = 0; m2 < 16; ++m2) mn += h1s[m2][t];
            mean1[t] = mn * (1.0f / 16.0f);
        }
        __syncthreads();
        if (t < 32) {
            float a = bs[t];
#pragma unroll
            for (int d = 0; d < 32; ++d) a += Wt[d][t] * u_vec[d];
#pragma unroll
            for (int d = 0; d < 32; ++d) a += Wt[32 + d][t] * mean1[d];
            v0[t] = fmaxf(a, 0.0f);
            float mv = 0.0f;
#pragma unroll
            for (int m2 = 0; m2 < 16; ++m2) mv += v1[m2][t];
            meanv1[t] = mv * (1.0f / 16.0f);
        }
        __syncthreads();
        if (t < 32) {
            float a = bs[t];
#pragma unroll
            for (int d = 0; d < 32; ++d) a += Wt[d][t] * v0[d];
#pragma unroll
            for (int d = 0; d < 32; ++d) a += Wt[32 + d][t] * meanv1[d];
            useru[t] += rule_w[r] * rws * tanhf(a);
        }
        __syncthreads();
    }

    if (t < 32) {
        const int it = items[b];
        const float x = emb[(long)it * DIMC + t];
        float sq = x * x;
        sq += __shfl_xor(sq, 1, 64);
        sq += __shfl_xor(sq, 2, 64);
        sq += __shfl_xor(sq, 4, 64);
        sq += __shfl_xor(sq, 8, 64);
        sq += __shfl_xor(sq, 16, 64);
        const float s = fminf(1.0f, 1.0f / fmaxf(sqrtf(sq), 1e-7f));
        float p = useru[t] * x * s;
        p += __shfl_xor(p, 1, 64);
        p += __shfl_xor(p, 2, 64);
        p += __shfl_xor(p, 4, 64);
        p += __shfl_xor(p, 8, 64);
        p += __shfl_xor(p, 16, 64);
        if (t == 0) out[b] = 1.0f / (1.0f + expf(-p));
    }
}

extern "C" void kernel_launch(void* const* d_in, const int* in_sizes, int n_in,
                              void* d_out, int out_size, void* d_ws, size_t ws_size,
                              hipStream_t stream) {
    const int*   users  = (const int*)d_in[0];
    const int*   items  = (const int*)d_in[1];
    const int*   rules  = (const int*)d_in[2];
    const int*   adj    = (const int*)d_in[3];
    const float* emb    = (const float*)d_in[4];
    const float* rule_w = (const float*)d_in[5];
    const float* W      = (const float*)d_in[6];
    const float* bvec   = (const float*)d_in[7];
    float*       out    = (float*)d_out;

    const int batch = in_sizes[0];  // 1024
    const size_t emb8_bytes = (size_t)E_NUMC * DIMC;                    // 3.2 MB
    const size_t whg_bytes  = (size_t)DIMC * 2 * DIMC * sizeof(short);  // 4 KB
    const size_t res_bytes  = (size_t)batch * RULESC * sizeof(float);   // 32 KB

    if (ws_size >= emb8_bytes + whg_bytes + res_bytes) {
        short*    emb8s = (short*)d_ws;
        _Float16* whg   = (_Float16*)((char*)d_ws + emb8_bytes);
        float*    resS  = (float*)((char*)d_ws + emb8_bytes + whg_bytes);

        renorm_kernel<<<dim3(E_NUMC / 16), dim3(256), 0, stream>>>(
            emb, emb8s, W, whg);
        rgrec_tree1w_kernel<<<dim3(batch, 2), dim3(256), 0, stream>>>(
            users, items, rules, adj, emb, (const uint2*)emb8s, whg, bvec, resS);
        rgrec_sig_kernel<<<dim3((batch + 255) / 256), dim3(256), 0, stream>>>(
            rule_w, resS, out, batch);
    } else {
        rgrec_fused_kernel<<<dim3(batch), dim3(256), 0, stream>>>(
            users, items, rules, adj, emb, rule_w, W, bvec, out);
    }
}

// Round 14
// 37.281 us; speedup vs baseline: 1.0999x; 1.0999x over previous
//
#include <hip/hip_runtime.h>
#include <hip/hip_fp16.h>
#include <math.h>

#define E_NUMC 100000
#define DIMC 32
#define NEIGHC 16
#define RULESC 8

struct __align__(16) h2x4 { __half2 x, y, z, w; };
struct __align__(8)  h2x2 { __half2 x, y; };

typedef _Float16 half8 __attribute__((ext_vector_type(8)));
typedef float    floatx4 __attribute__((ext_vector_type(4)));
typedef float    fx2 __attribute__((ext_vector_type(2)));

// ---------------------------------------------------------------------------
// Pre-pass: renormed embedding tables in d_ws.
//   emb16: fp16, 64 B/row  (hop1/user reads - accuracy-sensitive, unaveraged)
//   emb8:  fp8 e4m3, 32 B/row (hop2 reads - averaged over 16, 3.2 MB table
//          fits the 4 MB per-XCD L2 -> gathers become L2 hits)
// 16 lanes per row; lane j owns dims (2j, 2j+1).
// ---------------------------------------------------------------------------
__global__ __launch_bounds__(256) void renorm_kernel(
    const float* __restrict__ emb, __half2* __restrict__ o16,
    short* __restrict__ o8)
{
    const int row = blockIdx.x * 16 + (threadIdx.x >> 4);
    const int j = threadIdx.x & 15;
    const float2 f = ((const float2*)(emb + (long)row * DIMC))[j];
    float sq = f.x * f.x + f.y * f.y;
    sq += __shfl_xor(sq, 1, 64);
    sq += __shfl_xor(sq, 2, 64);
    sq += __shfl_xor(sq, 4, 64);
    sq += __shfl_xor(sq, 8, 64);
    const float s = fminf(1.0f, 1.0f / fmaxf(sqrtf(sq), 1e-7f));
    const float vx = f.x * s, vy = f.y * s;
    o16[(long)row * (DIMC / 2) + j] = __floats2half2_rn(vx, vy);
    const int pk = __builtin_amdgcn_cvt_pk_fp8_f32(vx, vy, 0, false);
    o8[(long)row * (DIMC / 2) + j] = (short)(pk & 0xffff);
}

// ---------------------------------------------------------------------------
// Kernel 1: one (batch, rule) tree per 256-thread block. 2 barriers.
// Phase B gathers hop2 rows from the fp8 table (uint2 = 8 dims per load),
// decodes with v_cvt_pk_f32_fp8, fp32-accumulates, 2-step butterfly.
// Phase D is a 16x32x64 GEMM via 4 x mfma_f32_16x16x32_f16 (C-frag:
// col=lane&15, row=4*(lane>>4)+reg); relu+bias+column-sum in-fragment
// produces meanv1 without materializing v1.
// ---------------------------------------------------------------------------
__global__ __launch_bounds__(256, 6) void rgrec_tree16_kernel(
    const int* __restrict__ users, const int* __restrict__ rules,
    const int* __restrict__ adj, const __half2* __restrict__ emb16,
    const uint2* __restrict__ emb8, const float* __restrict__ W,
    const float* __restrict__ bvec, float* __restrict__ res)
{
    const int b = blockIdx.x;
    const int r = blockIdx.y;
    const int t = threadIdx.x;
    const int lane = t & 63;
    const int wave = t >> 6;

    __shared__ _Float16 Xh[16][72];     // node rows: [h1 | mean2], 144B pitch
    __shared__ _Float16 Wh[32][72];     // W rows fp16, 144B pitch
    __shared__ _Float16 u16[72];        // user row (renormed)
    __shared__ float mean1p[2][36];     // partial sums of h1 rows (x8 each)
    __shared__ float xe[68];            // [v0 | meanv1]
    __shared__ float bs[32];

    const int user = users[b];
    const int rid0 = rules[r * 2 + 0];
    const int rid1 = rules[r * 2 + 1];

    // longest dependency chain first: hop1 ids (per-wave, no barrier)
    int h1v = 0;
    if (lane < 16) h1v = adj[(rid0 * E_NUMC + user) * NEIGHC + lane];

    // ---- phase B ids: node m, child j ----
    const int m = t >> 4;
    const int j = t & 15;
    const int e1 = __shfl(h1v, m, 64);
    const int e2 = adj[(rid1 * E_NUMC + e1) * NEIGHC + j];

    // ---- phase C loads issued early: 17 rows, 8 B/lane (fp16 table) ----
    const int g = t >> 3, k8 = t & 7;
    const bool cact = (t < 136);
    h2x2 craw;
    if (cact) {
        const int ec = (g < 16) ? __shfl(h1v, g, 64) : user;
        craw = ((const h2x2*)(emb16 + (long)ec * (DIMC / 2)))[k8];
    }

    // ---- stage W as fp16: thread -> (o = t>>3, oct = t&7), 8 floats ----
    {
        const float4* W4 = (const float4*)W;
        const int o = t >> 3, oct = t & 7;
        const float4 wa = W4[o * 16 + 2 * oct];
        const float4 wb = W4[o * 16 + 2 * oct + 1];
        half8 hw;
        hw[0] = (_Float16)wa.x; hw[1] = (_Float16)wa.y;
        hw[2] = (_Float16)wa.z; hw[3] = (_Float16)wa.w;
        hw[4] = (_Float16)wb.x; hw[5] = (_Float16)wb.y;
        hw[6] = (_Float16)wb.z; hw[7] = (_Float16)wb.w;
        *(half8*)&Wh[o][8 * oct] = hw;
    }
    if (t < 32) bs[t] = bvec[t];

    // ---- phase B: fp8 gather (uint2 = 8 dims) + decode + butterfly ----
    {
        const int k = j & 3;        // 8-dim chunk: dims 8k..8k+7 (8 bytes)
        const int h = j >> 2;       // child subset
        const int gbase = t & 48;   // wave-local base lane of this node group
        float acc[8];
#pragma unroll
        for (int d = 0; d < 8; ++d) acc[d] = 0.0f;
#pragma unroll
        for (int i = 0; i < 4; ++i) {
            const int ec = __shfl(e2, gbase + h + 4 * i, 64);
            const uint2 v = emb8[(long)ec * 4 + k];   // row = 4 x uint2
            const fx2 p0 = __builtin_amdgcn_cvt_pk_f32_fp8(v.x, false);
            const fx2 p1 = __builtin_amdgcn_cvt_pk_f32_fp8(v.x, true);
            const fx2 p2 = __builtin_amdgcn_cvt_pk_f32_fp8(v.y, false);
            const fx2 p3 = __builtin_amdgcn_cvt_pk_f32_fp8(v.y, true);
            acc[0] += p0[0]; acc[1] += p0[1];
            acc[2] += p1[0]; acc[3] += p1[1];
            acc[4] += p2[0]; acc[5] += p2[1];
            acc[6] += p3[0]; acc[7] += p3[1];
        }
#pragma unroll
        for (int d = 0; d < 8; ++d) acc[d] += __shfl_xor(acc[d], 4, 64);
#pragma unroll
        for (int d = 0; d < 8; ++d) acc[d] += __shfl_xor(acc[d], 8, 64);
        *(__half2*)&Xh[m][32 + 8 * k + 2 * h] =
            __floats2half2_rn(acc[2 * h] * (1.0f / 16.0f),
                              acc[2 * h + 1] * (1.0f / 16.0f));
    }

    // ---- phase C: store hop1/user rows + mean1 partial reduction ----
    if (cact) {
        if (g < 16) *(h2x2*)&Xh[g][4 * k8] = craw;
        else        *(h2x2*)&u16[4 * k8] = craw;
    }
    if (t < 128) {
        const float2 fa = __half22float2(craw.x);
        const float2 fb = __half22float2(craw.y);
        float c0 = fa.x, c1 = fa.y, c2 = fb.x, c3 = fb.y;
#pragma unroll
        for (int st = 8; st <= 32; st <<= 1) {
            c0 += __shfl_xor(c0, st, 64);
            c1 += __shfl_xor(c1, st, 64);
            c2 += __shfl_xor(c2, st, 64);
            c3 += __shfl_xor(c3, st, 64);
        }
        if ((lane & 56) == 0)   // lane < 8 (= k8)
            *(float4*)&mean1p[wave][4 * k8] = make_float4(c0, c1, c2, c3);
    }
    __syncthreads();   // barrier 1: Xh, u16, Wh, bs, mean1p visible

    const int cn = lane & 15;      // col (out) / row-id within fragments
    const int kg = lane >> 4;      // k-octet group
    if (wave < 2) {
        // ---- phase D: 16 nodes x 16 outs (N-half = wave), K = 64 ----
        const half8 a0 = *(const half8*)&Xh[cn][8 * kg];
        const half8 a1 = *(const half8*)&Xh[cn][32 + 8 * kg];
        const half8 b0 = *(const half8*)&Wh[cn + 16 * wave][8 * kg];
        const half8 b1 = *(const half8*)&Wh[cn + 16 * wave][32 + 8 * kg];
        floatx4 acc = {0.0f, 0.0f, 0.0f, 0.0f};
        acc = __builtin_amdgcn_mfma_f32_16x16x32_f16(a0, b0, acc, 0, 0, 0);
        acc = __builtin_amdgcn_mfma_f32_16x16x32_f16(a1, b1, acc, 0, 0, 0);
        const float bb = bs[cn + 16 * wave];
        float csum = 0.0f;
#pragma unroll
        for (int q = 0; q < 4; ++q) csum += fmaxf(acc[q] + bb, 0.0f);
        csum += __shfl_xor(csum, 16, 64);
        csum += __shfl_xor(csum, 32, 64);
        if (lane < 16) xe[32 + cn + 16 * wave] = csum * (1.0f / 16.0f);
    } else if (wave == 2) {
        // ---- v0 = relu(W [u | mean1] + b), split across d-halves ----
        const int o = lane & 31, h = lane >> 5;
        float a = 0.0f;
        if (h == 0) {
#pragma unroll
            for (int oct = 0; oct < 4; ++oct) {
                const half8 u = *(const half8*)&u16[8 * oct];
                const half8 w = *(const half8*)&Wh[o][8 * oct];
#pragma unroll
                for (int q = 0; q < 8; ++q) a += (float)u[q] * (float)w[q];
            }
        } else {
#pragma unroll
            for (int oct = 0; oct < 4; ++oct) {
                const half8 w = *(const half8*)&Wh[o][32 + 8 * oct];
                const float4 p0a = *(const float4*)&mean1p[0][8 * oct];
                const float4 p0b = *(const float4*)&mean1p[0][8 * oct + 4];
                const float4 p1a = *(const float4*)&mean1p[1][8 * oct];
                const float4 p1b = *(const float4*)&mean1p[1][8 * oct + 4];
                a += (float)w[0] * (p0a.x + p1a.x) + (float)w[1] * (p0a.y + p1a.y)
                   + (float)w[2] * (p0a.z + p1a.z) + (float)w[3] * (p0a.w + p1a.w)
                   + (float)w[4] * (p0b.x + p1b.x) + (float)w[5] * (p0b.y + p1b.y)
                   + (float)w[6] * (p0b.z + p1b.z) + (float)w[7] * (p0b.w + p1b.w);
            }
            a *= (1.0f / 16.0f);   // mean1 partials are sums over 16 rows
        }
        a += __shfl_xor(a, 32, 64);
        if (h == 0) xe[o] = fmaxf(a + bs[o], 0.0f);
    }
    __syncthreads();   // barrier 2: xe ready

    // ---- phase E: wave 0, out o, halves over d ----
    if (t < 64) {
        const int o = lane & 31, h = lane >> 5;
        float a = 0.0f;
#pragma unroll
        for (int oct = 4 * h; oct < 4 * h + 4; ++oct) {
            const half8 w = *(const half8*)&Wh[o][8 * oct];
            const float4 xa = *(const float4*)&xe[8 * oct];
            const float4 xb = *(const float4*)&xe[8 * oct + 4];
            a += (float)w[0] * xa.x + (float)w[1] * xa.y
               + (float)w[2] * xa.z + (float)w[3] * xa.w
               + (float)w[4] * xb.x + (float)w[5] * xb.y
               + (float)w[6] * xb.z + (float)w[7] * xb.w;
        }
        a += __shfl_xor(a, 32, 64);
        if (h == 0)
            res[(b * RULESC + r) * DIMC + o] = tanhf(a + bs[o]);
    }
}

// ---------------------------------------------------------------------------
// Kernel 2: one wave per batch element — rule-weighted sum + item dot+sigmoid
// (item row renormed from the ORIGINAL fp32 table for final accuracy)
// ---------------------------------------------------------------------------
__global__ __launch_bounds__(256) void rgrec_combine_kernel(
    const int* __restrict__ items, const float* __restrict__ emb,
    const float* __restrict__ rule_w, const float* __restrict__ res,
    float* __restrict__ out, int B)
{
    const int gw = (blockIdx.x * 256 + threadIdx.x) >> 6;
    const int lane = threadIdx.x & 63;
    if (gw >= B) return;
    const int b = gw;

    float ss = 0.0f;
#pragma unroll
    for (int i = 0; i < RULESC; ++i) { const float w = rule_w[i]; ss += w * w; }
    const float rws = fminf(1.0f, 1.0f / fmaxf(sqrtf(ss), 1e-7f));

    const int d = lane & 31, rh = lane >> 5;
    float acc = 0.0f;
#pragma unroll
    for (int rr = 0; rr < 4; ++rr) {
        const int r = rh * 4 + rr;
        acc += rule_w[r] * res[(b * RULESC + r) * DIMC + d];
    }
    acc += __shfl_xor(acc, 32, 64);
    acc *= rws;

    const int it = items[b];
    const float x = emb[(long)it * DIMC + d];
    float sq = x * x;
    sq += __shfl_xor(sq, 1, 64);
    sq += __shfl_xor(sq, 2, 64);
    sq += __shfl_xor(sq, 4, 64);
    sq += __shfl_xor(sq, 8, 64);
    sq += __shfl_xor(sq, 16, 64);
    const float s = fminf(1.0f, 1.0f / fmaxf(sqrtf(sq), 1e-7f));
    float p = acc * x * s;
    p += __shfl_xor(p, 1, 64);
    p += __shfl_xor(p, 2, 64);
    p += __shfl_xor(p, 4, 64);
    p += __shfl_xor(p, 8, 64);
    p += __shfl_xor(p, 16, 64);
    if (lane == 0) out[b] = 1.0f / (1.0f + expf(-p));
}

// ---------------------------------------------------------------------------
// Fallback fused fp32 kernel (known-good) if d_ws is too small.
// ---------------------------------------------------------------------------
__global__ __launch_bounds__(256) void rgrec_fused_kernel(
    const int* __restrict__ users, const int* __restrict__ items,
    const int* __restrict__ rules, const int* __restrict__ adj,
    const float* __restrict__ emb, const float* __restrict__ rule_w,
    const float* __restrict__ W, const float* __restrict__ bvec,
    float* __restrict__ out)
{
    const int b = blockIdx.x;
    const int t = threadIdx.x;

    __shared__ float Wt[64][33];
    __shared__ float bs[32];
    __shared__ float h1s[16][33];
    __shared__ float mean2[16][33];
    __shared__ float v1[16][33];
    __shared__ float u_vec[32];
    __shared__ float mean1[32];
    __shared__ float v0[32];
    __shared__ float meanv1[32];
    __shared__ float useru[32];
    __shared__ int   h1id[16];

    for (int i = t; i < 64 * 32; i += 256) {
        const int o = i >> 6, d = i & 63;
        Wt[d][o] = W[i];
    }
    if (t < 32) { bs[t] = bvec[t]; useru[t] = 0.0f; }

    float ss = 0.0f;
#pragma unroll
    for (int i = 0; i < RULESC; ++i) { const float w = rule_w[i]; ss += w * w; }
    const float rws = fminf(1.0f, 1.0f / fmaxf(sqrtf(ss), 1e-7f));

    const int user = users[b];

    for (int r = 0; r < RULESC; ++r) {
        const int rid0 = rules[r * 2 + 0];
        const int rid1 = rules[r * 2 + 1];
        if (t < 16) h1id[t] = adj[(rid0 * E_NUMC + user) * NEIGHC + t];
        __syncthreads();
        {
            const int m = t >> 4, j = t & 15;
            const int e1 = h1id[m];
            const int e2 = adj[(rid1 * E_NUMC + e1) * NEIGHC + j];
            float v[32];
            const float4* p = (const float4*)(emb + (long)e2 * DIMC);
            float sq = 0.0f;
#pragma unroll
            for (int q = 0; q < 8; ++q) {
                const float4 f = p[q];
                v[q * 4 + 0] = f.x; v[q * 4 + 1] = f.y;
                v[q * 4 + 2] = f.z; v[q * 4 + 3] = f.w;
                sq += f.x * f.x + f.y * f.y + f.z * f.z + f.w * f.w;
            }
            const float s =
                fminf(1.0f, 1.0f / fmaxf(sqrtf(sq), 1e-7f)) * (1.0f / 16.0f);
#pragma unroll
            for (int d = 0; d < 32; ++d) v[d] *= s;
#pragma unroll
            for (int st = 1; st < 16; st <<= 1) {
#pragma unroll
                for (int d = 0; d < 32; ++d) v[d] += __shfl_xor(v[d], st, 64);
            }
            mean2[m][j]      = v[j];
            mean2[m][j + 16] = v[j + 16];
        }
        if (t < 136) {
            const int g = t >> 3, k = t & 7;
            const int e = (g < 16) ? h1id[g] : user;
            const float4 f = ((const float4*)(emb + (long)e * DIMC))[k];
            float sq = f.x * f.x + f.y * f.y + f.z * f.z + f.w * f.w;
            sq += __shfl_xor(sq, 1, 64);
            sq += __shfl_xor(sq, 2, 64);
            sq += __shfl_xor(sq, 4, 64);
            const float s = fminf(1.0f, 1.0f / fmaxf(sqrtf(sq), 1e-7f));
            if (g < 16) {
                h1s[g][k * 4 + 0] = f.x * s; h1s[g][k * 4 + 1] = f.y * s;
                h1s[g][k * 4 + 2] = f.z * s; h1s[g][k * 4 + 3] = f.w * s;
            } else {
                u_vec[k * 4 + 0] = f.x * s; u_vec[k * 4 + 1] = f.y * s;
                u_vec[k * 4 + 2] = f.z * s; u_vec[k * 4 + 3] = f.w * s;
            }
        }
        __syncthreads();
        {
            const int m = t >> 4, o = t & 15;
            float a0 = bs[o], a1 = bs[o + 16];
#pragma unroll
            for (int d = 0; d < 32; ++d) {
                const float h = h1s[m][d];
                a0 += Wt[d][o] * h;
                a1 += Wt[d][o + 16] * h;
            }
#pragma unroll
            for (int d = 0; d < 32; ++d) {
                const float h = mean2[m][d];
                a0 += Wt[32 + d][o] * h;
                a1 += Wt[32 + d][o + 16] * h;
            }
            v1[m][o]      = fmaxf(a0, 0.0f);
            v1[m][o + 16] = fmaxf(a1, 0.0f);
        }
        if (t < 32) {
            float mn = 0.0f;
#pragma unroll
            for (int m2 = 0; m2 < 16; ++m2) mn += h1s[m2][t];
            mean1[t] = mn * (1.0f / 16.0f);
        }
        __syncthreads();
        if (t < 32) {
            float a = bs[t];
#pragma unroll
            for (int d = 0; d < 32; ++d) a += Wt[d][t] * u_vec[d];
#pragma unroll
            for (int d = 0; d < 32; ++d) a += Wt[32 + d][t] * mean1[d];
            v0[t] = fmaxf(a, 0.0f);
            float mv = 0.0f;
#pragma unroll
            for (int m2 = 0; m2 < 16; ++m2) mv += v1[m2][t];
            meanv1[t] = mv * (1.0f / 16.0f);
        }
        __syncthreads();
        if (t < 32) {
            float a = bs[t];
#pragma unroll
            for (int d = 0; d < 32; ++d) a += Wt[d][t] * v0[d];
#pragma unroll
            for (int d = 0; d < 32; ++d) a += Wt[32 + d][t] * meanv1[d];
            useru[t] += rule_w[r] * rws * tanhf(a);
        }
        __syncthreads();
    }

    if (t < 32) {
        const int it = items[b];
        const float x = emb[(long)it * DIMC + t];
        float sq = x * x;
        sq += __shfl_xor(sq, 1, 64);
        sq += __shfl_xor(sq, 2, 64);
        sq += __shfl_xor(sq, 4, 64);
        sq += __shfl_xor(sq, 8, 64);
        sq += __shfl_xor(sq, 16, 64);
        const float s = fminf(1.0f, 1.0f / fmaxf(sqrtf(sq), 1e-7f));
        float p = useru[t] * x * s;
        p += __shfl_xor(p, 1, 64);
        p += __shfl_xor(p, 2, 64);
        p += __shfl_xor(p, 4, 64);
        p += __shfl_xor(p, 8, 64);
        p += __shfl_xor(p, 16, 64);
        if (t == 0) out[b] = 1.0f / (1.0f + expf(-p));
    }
}

extern "C" void kernel_launch(void* const* d_in, const int* in_sizes, int n_in,
                              void* d_out, int out_size, void* d_ws, size_t ws_size,
                              hipStream_t stream) {
    const int*   users  = (const int*)d_in[0];
    const int*   items  = (const int*)d_in[1];
    const int*   rules  = (const int*)d_in[2];
    const int*   adj    = (const int*)d_in[3];
    const float* emb    = (const float*)d_in[4];
    const float* rule_w = (const float*)d_in[5];
    const float* W      = (const float*)d_in[6];
    const float* bvec   = (const float*)d_in[7];
    float*       out    = (float*)d_out;

    const int batch = in_sizes[0];  // 1024
    const size_t emb16_bytes = (size_t)E_NUMC * DIMC * sizeof(__half);  // 6.4 MB
    const size_t emb8_bytes  = (size_t)E_NUMC * DIMC;                   // 3.2 MB
    const size_t res_bytes   = (size_t)batch * RULESC * DIMC * sizeof(float);

    if (ws_size >= emb16_bytes + emb8_bytes + res_bytes) {
        __half2* emb16 = (__half2*)d_ws;
        short*   emb8s = (short*)((char*)d_ws + emb16_bytes);
        float*   res   = (float*)((char*)d_ws + emb16_bytes + emb8_bytes);

        renorm_kernel<<<dim3(E_NUMC / 16), dim3(256), 0, stream>>>(
            emb, emb16, emb8s);
        rgrec_tree16_kernel<<<dim3(batch, RULESC), dim3(256), 0, stream>>>(
            users, rules, adj, emb16, (const uint2*)emb8s, W, bvec, res);
        const int nblk = (batch * 64 + 255) / 256;
        rgrec_combine_kernel<<<dim3(nblk), dim3(256), 0, stream>>>(
            items, emb, rule_w, res, out, batch);
    } else {
        rgrec_fused_kernel<<<dim3(batch), dim3(256), 0, stream>>>(
            users, items, rules, adj, emb, rule_w, W, bvec, out);
    }
}